// Round 16
// baseline (202.369 us; speedup 1.0000x reference)
//
#include <hip/hip_runtime.h>
#include <hip/hip_fp16.h>

#define HH 256
#define WW 256
#define CC 64
#define BB 2
#define KK2 9
#define HWSZ (HH * WW)

#define TH 8
#define TW 32
#define NR 18                 // window rows [h0-5, h0+12]
#define NC 44                 // window cols [w0-5, w0+38]
#define NRC (NR * NC)         // 792 slots
#define PSTRIDE (NRC + 1)     // +1 quad pad between the 2 resident planes

struct __align__(16) H8 { __half2 h[4]; };   // 8 halves = 16 B

// ---------------- transpose+convert: x[b][c][h][w] f32 -> xT[b][h][w][c] f16 ----------------
__global__ __launch_bounds__(256, 4) void transpose_nchw_to_nhwc_f16(
    const float* __restrict__ x, __half* __restrict__ xT)
{
    __shared__ float tile[CC][65];
    const int row = blockIdx.x;
    const int h   = row & (HH - 1);
    const int b   = row >> 8;
    const int w0  = blockIdx.y * 64;
    const int lw  = threadIdx.x & 63;
    const int lr  = threadIdx.x >> 6;

    const float* xp = x + (size_t)b * CC * HWSZ + h * WW + w0;
#pragma unroll
    for (int p = 0; p < 16; ++p) {
        int c = p * 4 + lr;
        tile[c][lw] = xp[(size_t)c * HWSZ + lw];
    }
    __syncthreads();

    __half2* xo2 = (__half2*)(xT + ((size_t)(b * HH + h) * WW + w0) * CC);
    const int m  = threadIdx.x & 31;
    const int w8 = threadIdx.x >> 5;
#pragma unroll
    for (int q = 0; q < 8; ++q) {
        int wl = w8 + q * 8;
        float lo = tile[2 * m][wl];
        float hi = tile[2 * m + 1][wl];
        xo2[wl * 32 + m] = __floats2half2_rn(lo, hi);
    }
}

// ---------------- main: R13 structure, two-phase channel split ----------------
// 1024 blocks x 256 threads. Block = 8x32 px x 32 ch (c-half), processed as two
// 16-ch phases sharing a 25.4 KB LDS window -> 6 blocks/CU = 24 waves/CU (2x R13).
// offset/mask loads hoisted once (R13 win); per phase: stage 2 quad-planes via
// ds_write_b128, barrier, pure ds_read_b128 + v_pk_fma_f16 k-loop, store 16 ch.
__global__ __launch_bounds__(256, 6) void dcn_lds(
    const __half* __restrict__ xT,
    const float* __restrict__ offset,
    const float* __restrict__ mask,
    const float* __restrict__ weight,
    float* __restrict__ out)
{
    __shared__ __half smem[2 * PSTRIDE * 8];   // 25376 B

    const int nb = BB * (HH / TH) * (WW / TW) * 2;   // 1024
    int flat = blockIdx.x;
    int sb = (flat & 7) * (nb >> 3) + (flat >> 3);   // XCD-chunked, row-band sequential
    const int half = sb & 1;
    const int tw   = (sb >> 1) & 7;
    const int th   = (sb >> 4) & 31;
    const int b    = sb >> 9;

    const int h0 = th * TH, w0 = tw * TW;
    const int r0 = h0 - 5, c0 = w0 - 5;
    const int r1 = r0 + NR - 1, c1 = c0 + NC - 1;

    const int t  = threadIdx.x;
    const int tr = t >> 5, tc = t & 31;
    const int h  = h0 + tr, w = w0 + tc;
    const int hw = h * WW + w;

    const __half* xbase = xT + (size_t)b * HWSZ * CC + half * 32;

    // ---- hoisted param loads (issued once; latency drains under staging) ----
    const float* offb  = offset + (size_t)b * 2 * KK2 * HWSZ + hw;
    const float* maskb = mask   + (size_t)b * KK2 * HWSZ + hw;

    float offy[KK2], offx[KK2], mv[KK2];
#pragma unroll
    for (int k = 0; k < KK2; ++k) {
        offy[k] = offb[(2 * k)     * HWSZ];
        offx[k] = offb[(2 * k + 1) * HWSZ];
    }
#pragma unroll
    for (int k = 0; k < KK2; ++k) {
        mv[k] = maskb[k * HWSZ] * weight[k];
    }

    for (int p = 0; p < 2; ++p) {
        if (p) __syncthreads();   // all reads of previous window done

        // ---- stage 16-channel window: 2 quads (32 B) per px slot ----
        for (int idx = t; idx < NRC; idx += 256) {
            int r = idx / NC, c = idx - NC * r;
            int rs = min(max(r0 + r, 0), HH - 1);
            int cs = min(max(c0 + c, 0), WW - 1);
            const H8* src = (const H8*)(xbase + (size_t)(rs * WW + cs) * CC);
#pragma unroll
            for (int u = 0; u < 2; ++u)
                *(H8*)&smem[(u * PSTRIDE + idx) * 8] = src[2 * p + u];
        }

        float acc[16];
#pragma unroll
        for (int i = 0; i < 16; ++i) acc[i] = 0.f;

        __syncthreads();

#pragma unroll
        for (int ki = 0; ki < 3; ++ki) {
            __half2 hacc[8];
#pragma unroll
            for (int i = 0; i < 8; ++i) hacc[i] = __floats2half2_rn(0.f, 0.f);

#pragma unroll
            for (int kj = 0; kj < 3; ++kj) {
                const int k = ki * 3 + kj;

                float py = (float)(h - 1 + ki) + offy[k];
                float px = (float)(w - 1 + kj) + offx[k];
                float y0f = floorf(py), x0f = floorf(px);
                float ly = py - y0f, lx = px - x0f;
                float hy = 1.f - ly, hx = 1.f - lx;
                int y0 = (int)y0f, x0 = (int)x0f;
                int y1 = y0 + 1,   x1 = x0 + 1;

                bool vy0 = (unsigned)y0 < (unsigned)HH;
                bool vy1 = (unsigned)y1 < (unsigned)HH;
                bool vx0 = (unsigned)x0 < (unsigned)WW;
                bool vx1 = (unsigned)x1 < (unsigned)WW;
                int y0c = min(max(y0, 0), HH - 1);
                int y1c = min(max(y1, 0), HH - 1);
                int x0c = min(max(x0, 0), WW - 1);
                int x1c = min(max(x1, 0), WW - 1);

                __half2 w00h = __float2half2_rn(hy * hx * mv[k] * (float)(vy0 && vx0));
                __half2 w01h = __float2half2_rn(hy * lx * mv[k] * (float)(vy0 && vx1));
                __half2 w10h = __float2half2_rn(ly * hx * mv[k] * (float)(vy1 && vx0));
                __half2 w11h = __float2half2_rn(ly * lx * mv[k] * (float)(vy1 && vx1));

                bool iw = (y0c >= r0) & (y1c <= r1) & (x0c >= c0) & (x1c <= c1);
                if (iw) {
                    int s00 = (y0c - r0) * NC + (x0c - c0);
                    int s01 = s00 + (x1c - x0c);
                    int s10 = (y1c - r0) * NC + (x0c - c0);
                    int s11 = s10 + (x1c - x0c);
#pragma unroll
                    for (int u = 0; u < 2; ++u) {
                        const int pb = u * PSTRIDE * 8;
                        H8 v00 = *(const H8*)&smem[pb + s00 * 8];
                        H8 v01 = *(const H8*)&smem[pb + s01 * 8];
                        H8 v10 = *(const H8*)&smem[pb + s10 * 8];
                        H8 v11 = *(const H8*)&smem[pb + s11 * 8];
#pragma unroll
                        for (int q = 0; q < 4; ++q) {
                            __half2 a = hacc[u * 4 + q];
                            a = __hfma2(w00h, v00.h[q], a);
                            a = __hfma2(w01h, v01.h[q], a);
                            a = __hfma2(w10h, v10.h[q], a);
                            a = __hfma2(w11h, v11.h[q], a);
                            hacc[u * 4 + q] = a;
                        }
                    }
                } else {
                    const H8* g00 = (const H8*)(xbase + (size_t)(y0c * WW + x0c) * CC);
                    const H8* g01 = (const H8*)(xbase + (size_t)(y0c * WW + x1c) * CC);
                    const H8* g10 = (const H8*)(xbase + (size_t)(y1c * WW + x0c) * CC);
                    const H8* g11 = (const H8*)(xbase + (size_t)(y1c * WW + x1c) * CC);
#pragma unroll
                    for (int u = 0; u < 2; ++u) {
                        H8 v00 = g00[2 * p + u];
                        H8 v01 = g01[2 * p + u];
                        H8 v10 = g10[2 * p + u];
                        H8 v11 = g11[2 * p + u];
#pragma unroll
                        for (int q = 0; q < 4; ++q) {
                            __half2 a = hacc[u * 4 + q];
                            a = __hfma2(w00h, v00.h[q], a);
                            a = __hfma2(w01h, v01.h[q], a);
                            a = __hfma2(w10h, v10.h[q], a);
                            a = __hfma2(w11h, v11.h[q], a);
                            hacc[u * 4 + q] = a;
                        }
                    }
                }
            }

            // flush the 3-k group to f32
#pragma unroll
            for (int i = 0; i < 8; ++i) {
                float2 f = __half22float2(hacc[i]);
                acc[2 * i]     += f.x;
                acc[2 * i + 1] += f.y;
            }
        }

        float* ob = out + ((size_t)b * CC + half * 32 + p * 16) * HWSZ + hw;
#pragma unroll
        for (int i = 0; i < 16; ++i) ob[i * HWSZ] = acc[i];
    }
}

// ---------------- fallback (NCHW direct) ----------------
__global__ __launch_bounds__(256, 4) void dcn_kernel(
    const float* __restrict__ x,
    const float* __restrict__ offset,
    const float* __restrict__ mask,
    const float* __restrict__ weight,
    float* __restrict__ out)
{
    const int w   = threadIdx.x;
    const int row = blockIdx.x;
    const int h   = row & (HH - 1);
    const int b   = row >> 8;
    const int c0  = blockIdx.y * 16;
    const int hw  = h * WW + w;

    const float* offb  = offset + (size_t)b * 2 * KK2 * HWSZ + hw;
    const float* maskb = mask   + (size_t)b * KK2 * HWSZ + hw;
    const float* xb0   = x      + ((size_t)b * CC + c0) * HWSZ;

    float acc[16];
#pragma unroll
    for (int c = 0; c < 16; ++c) acc[c] = 0.f;

    for (int k = 0; k < KK2; ++k) {
        const int ki = k / 3;
        const int kj = k - 3 * ki;
        float offy = offb[(2 * k)     * HWSZ];
        float offx = offb[(2 * k + 1) * HWSZ];
        float mval = maskb[k * HWSZ] * weight[k];

        float py = (float)(h - 1 + ki) + offy;
        float px = (float)(w - 1 + kj) + offx;
        float y0f = floorf(py), x0f = floorf(px);
        float ly = py - y0f, lx = px - x0f;
        float hy = 1.f - ly, hx = 1.f - lx;
        int y0 = (int)y0f, x0 = (int)x0f;
        int y1 = y0 + 1,   x1 = x0 + 1;

        bool vy0 = (unsigned)y0 < (unsigned)HH;
        bool vy1 = (unsigned)y1 < (unsigned)HH;
        bool vx0 = (unsigned)x0 < (unsigned)WW;
        bool vx1 = (unsigned)x1 < (unsigned)WW;
        int y0c = min(max(y0, 0), HH - 1);
        int y1c = min(max(y1, 0), HH - 1);
        int x0c = min(max(x0, 0), WW - 1);
        int x1c = min(max(x1, 0), WW - 1);

        float w00 = hy * hx * mval * (float)(vy0 && vx0);
        float w01 = hy * lx * mval * (float)(vy0 && vx1);
        float w10 = ly * hx * mval * (float)(vy1 && vx0);
        float w11 = ly * lx * mval * (float)(vy1 && vx1);

        int i00 = y0c * WW + x0c;
        int i01 = y0c * WW + x1c;
        int i10 = y1c * WW + x0c;
        int i11 = y1c * WW + x1c;

        const float* xb = xb0;
#pragma unroll
        for (int c = 0; c < 16; ++c) {
            acc[c] = fmaf(w00, xb[i00],
                     fmaf(w01, xb[i01],
                     fmaf(w10, xb[i10],
                     fmaf(w11, xb[i11], acc[c]))));
            xb += HWSZ;
        }
    }

    float* ob = out + ((size_t)b * CC + c0) * HWSZ + hw;
#pragma unroll
    for (int c = 0; c < 16; ++c) ob[c * HWSZ] = acc[c];
}

extern "C" void kernel_launch(void* const* d_in, const int* in_sizes, int n_in,
                              void* d_out, int out_size, void* d_ws, size_t ws_size,
                              hipStream_t stream) {
    const float* x      = (const float*)d_in[0];
    const float* offset = (const float*)d_in[1];
    const float* mask   = (const float*)d_in[2];
    const float* weight = (const float*)d_in[3];
    float* out = (float*)d_out;

    const size_t xT_bytes = (size_t)BB * CC * HWSZ * sizeof(__half);
    if (ws_size >= xT_bytes) {
        __half* xT = (__half*)d_ws;
        dim3 tgrid(BB * HH, WW / 64);
        transpose_nchw_to_nhwc_f16<<<tgrid, 256, 0, stream>>>(x, xT);
        dcn_lds<<<BB * (HH / TH) * (WW / TW) * 2, 256, 0, stream>>>(
            xT, offset, mask, weight, out);
    } else {
        dim3 grid(BB * HH, CC / 16);
        dcn_kernel<<<grid, 256, 0, stream>>>(x, offset, mask, weight, out);
    }
}

// Round 17
// 39.222 us; speedup vs baseline: 5.1596x; 5.1596x over previous
//
#include <hip/hip_runtime.h>
#include <hip/hip_fp16.h>

#define HH 256
#define WW 256
#define CC 64
#define BB 2
#define KK2 9
#define HWSZ (HH * WW)

#define TH 8
#define TW 32
#define NR 18                 // window rows [h0-5, h0+12]
#define NC 44                 // window cols [w0-5, w0+38]
#define NRC (NR * NC)         // 792 slots
#define PSTRIDE (NRC + 1)     // +1 quad pad between planes

struct __align__(16) H8 { __half2 h[4]; };   // 8 halves = 16 B

// ---------------- transpose+convert: x[b][c][h][w] f32 -> xT[b][h][w][c] f16 ----------------
__global__ __launch_bounds__(256, 4) void transpose_nchw_to_nhwc_f16(
    const float* __restrict__ x, __half* __restrict__ xT)
{
    __shared__ float tile[CC][65];
    const int row = blockIdx.x;
    const int h   = row & (HH - 1);
    const int b   = row >> 8;
    const int w0  = blockIdx.y * 64;
    const int lw  = threadIdx.x & 63;
    const int lr  = threadIdx.x >> 6;

    const float* xp = x + (size_t)b * CC * HWSZ + h * WW + w0;
#pragma unroll
    for (int p = 0; p < 16; ++p) {
        int c = p * 4 + lr;
        tile[c][lw] = xp[(size_t)c * HWSZ + lw];
    }
    __syncthreads();

    __half2* xo2 = (__half2*)(xT + ((size_t)(b * HH + h) * WW + w0) * CC);
    const int m  = threadIdx.x & 31;
    const int w8 = threadIdx.x >> 5;
#pragma unroll
    for (int q = 0; q < 8; ++q) {
        int wl = w8 + q * 8;
        float lo = tile[2 * m][wl];
        float hi = tile[2 * m + 1][wl];
        xo2[wl * 32 + m] = __floats2half2_rn(lo, hi);
    }
}

// ---------------- main: LDS-staged bilinear gather (R13 best: param-load hoist) ----------------
// 1024 blocks x 256 threads. Block = 8x32 px x 32 ch (c-half). Window 18x44 fp16
// in LDS (50.7 KB). The 27 offset/mask loads are issued BEFORE the staging loop
// so their L2 latency drains under staging + __syncthreads; weights/coords are
// computed in-loop (cheap VALU, low register pressure). k-loop: ds_read_b128 +
// v_pk_fma_f16 only.
__global__ __launch_bounds__(256, 2) void dcn_lds(
    const __half* __restrict__ xT,
    const float* __restrict__ offset,
    const float* __restrict__ mask,
    const float* __restrict__ weight,
    float* __restrict__ out)
{
    __shared__ __half smem[4 * PSTRIDE * 8];   // 50752 B

    const int nb = BB * (HH / TH) * (WW / TW) * 2;   // 1024
    int flat = blockIdx.x;
    int sb = (flat & 7) * (nb >> 3) + (flat >> 3);   // XCD-chunked, row-band sequential
    const int half = sb & 1;
    const int tw   = (sb >> 1) & 7;
    const int th   = (sb >> 4) & 31;
    const int b    = sb >> 9;

    const int h0 = th * TH, w0 = tw * TW;
    const int r0 = h0 - 5, c0 = w0 - 5;
    const int r1 = r0 + NR - 1, c1 = c0 + NC - 1;

    const int t  = threadIdx.x;
    const int tr = t >> 5, tc = t & 31;
    const int h  = h0 + tr, w = w0 + tc;
    const int hw = h * WW + w;

    const __half* xbase = xT + (size_t)b * HWSZ * CC + half * 32;

    // ---- issue all per-k param loads FIRST (latency hides under staging+barrier) ----
    const float* offb  = offset + (size_t)b * 2 * KK2 * HWSZ + hw;
    const float* maskb = mask   + (size_t)b * KK2 * HWSZ + hw;

    float offy[KK2], offx[KK2], mv[KK2];
#pragma unroll
    for (int k = 0; k < KK2; ++k) {
        offy[k] = offb[(2 * k)     * HWSZ];
        offx[k] = offb[(2 * k + 1) * HWSZ];
    }
#pragma unroll
    for (int k = 0; k < KK2; ++k) {
        mv[k] = maskb[k * HWSZ] * weight[k];
    }

    // ---- stage window: 4 quads (64 B) per px slot ----
    for (int idx = t; idx < NRC; idx += 256) {
        int r = idx / NC, c = idx - NC * r;
        int rs = min(max(r0 + r, 0), HH - 1);
        int cs = min(max(c0 + c, 0), WW - 1);
        const H8* src = (const H8*)(xbase + (size_t)(rs * WW + cs) * CC);
#pragma unroll
        for (int u = 0; u < 4; ++u)
            *(H8*)&smem[(u * PSTRIDE + idx) * 8] = src[u];
    }

    float acc[32];
#pragma unroll
    for (int i = 0; i < 32; ++i) acc[i] = 0.f;

    __syncthreads();

#pragma unroll
    for (int ki = 0; ki < 3; ++ki) {
        __half2 hacc[16];
#pragma unroll
        for (int i = 0; i < 16; ++i) hacc[i] = __floats2half2_rn(0.f, 0.f);

#pragma unroll
        for (int kj = 0; kj < 3; ++kj) {
            const int k = ki * 3 + kj;

            float py = (float)(h - 1 + ki) + offy[k];
            float px = (float)(w - 1 + kj) + offx[k];
            float y0f = floorf(py), x0f = floorf(px);
            float ly = py - y0f, lx = px - x0f;
            float hy = 1.f - ly, hx = 1.f - lx;
            int y0 = (int)y0f, x0 = (int)x0f;
            int y1 = y0 + 1,   x1 = x0 + 1;

            bool vy0 = (unsigned)y0 < (unsigned)HH;
            bool vy1 = (unsigned)y1 < (unsigned)HH;
            bool vx0 = (unsigned)x0 < (unsigned)WW;
            bool vx1 = (unsigned)x1 < (unsigned)WW;
            int y0c = min(max(y0, 0), HH - 1);
            int y1c = min(max(y1, 0), HH - 1);
            int x0c = min(max(x0, 0), WW - 1);
            int x1c = min(max(x1, 0), WW - 1);

            __half2 w00h = __float2half2_rn(hy * hx * mv[k] * (float)(vy0 && vx0));
            __half2 w01h = __float2half2_rn(hy * lx * mv[k] * (float)(vy0 && vx1));
            __half2 w10h = __float2half2_rn(ly * hx * mv[k] * (float)(vy1 && vx0));
            __half2 w11h = __float2half2_rn(ly * lx * mv[k] * (float)(vy1 && vx1));

            bool iw = (y0c >= r0) & (y1c <= r1) & (x0c >= c0) & (x1c <= c1);
            if (iw) {
                int s00 = (y0c - r0) * NC + (x0c - c0);
                int s01 = s00 + (x1c - x0c);
                int s10 = (y1c - r0) * NC + (x0c - c0);
                int s11 = s10 + (x1c - x0c);
#pragma unroll
                for (int u = 0; u < 4; ++u) {
                    const int pb = u * PSTRIDE * 8;
                    H8 v00 = *(const H8*)&smem[pb + s00 * 8];
                    H8 v01 = *(const H8*)&smem[pb + s01 * 8];
                    H8 v10 = *(const H8*)&smem[pb + s10 * 8];
                    H8 v11 = *(const H8*)&smem[pb + s11 * 8];
#pragma unroll
                    for (int q = 0; q < 4; ++q) {
                        __half2 a = hacc[u * 4 + q];
                        a = __hfma2(w00h, v00.h[q], a);
                        a = __hfma2(w01h, v01.h[q], a);
                        a = __hfma2(w10h, v10.h[q], a);
                        a = __hfma2(w11h, v11.h[q], a);
                        hacc[u * 4 + q] = a;
                    }
                }
            } else {
                const H8* g00 = (const H8*)(xbase + (size_t)(y0c * WW + x0c) * CC);
                const H8* g01 = (const H8*)(xbase + (size_t)(y0c * WW + x1c) * CC);
                const H8* g10 = (const H8*)(xbase + (size_t)(y1c * WW + x0c) * CC);
                const H8* g11 = (const H8*)(xbase + (size_t)(y1c * WW + x1c) * CC);
#pragma unroll
                for (int u = 0; u < 4; ++u) {
                    H8 v00 = g00[u];
                    H8 v01 = g01[u];
                    H8 v10 = g10[u];
                    H8 v11 = g11[u];
#pragma unroll
                    for (int q = 0; q < 4; ++q) {
                        __half2 a = hacc[u * 4 + q];
                        a = __hfma2(w00h, v00.h[q], a);
                        a = __hfma2(w01h, v01.h[q], a);
                        a = __hfma2(w10h, v10.h[q], a);
                        a = __hfma2(w11h, v11.h[q], a);
                        hacc[u * 4 + q] = a;
                    }
                }
            }
        }

        // flush the 3-k group to f32
#pragma unroll
        for (int i = 0; i < 16; ++i) {
            float2 f = __half22float2(hacc[i]);
            acc[2 * i]     += f.x;
            acc[2 * i + 1] += f.y;
        }
    }

    float* ob = out + ((size_t)b * CC + half * 32) * HWSZ + hw;
#pragma unroll
    for (int i = 0; i < 32; ++i) ob[i * HWSZ] = acc[i];
}

// ---------------- fallback (NCHW direct) ----------------
__global__ __launch_bounds__(256, 4) void dcn_kernel(
    const float* __restrict__ x,
    const float* __restrict__ offset,
    const float* __restrict__ mask,
    const float* __restrict__ weight,
    float* __restrict__ out)
{
    const int w   = threadIdx.x;
    const int row = blockIdx.x;
    const int h   = row & (HH - 1);
    const int b   = row >> 8;
    const int c0  = blockIdx.y * 16;
    const int hw  = h * WW + w;

    const float* offb  = offset + (size_t)b * 2 * KK2 * HWSZ + hw;
    const float* maskb = mask   + (size_t)b * KK2 * HWSZ + hw;
    const float* xb0   = x      + ((size_t)b * CC + c0) * HWSZ;

    float acc[16];
#pragma unroll
    for (int c = 0; c < 16; ++c) acc[c] = 0.f;

    for (int k = 0; k < KK2; ++k) {
        const int ki = k / 3;
        const int kj = k - 3 * ki;
        float offy = offb[(2 * k)     * HWSZ];
        float offx = offb[(2 * k + 1) * HWSZ];
        float mval = maskb[k * HWSZ] * weight[k];

        float py = (float)(h - 1 + ki) + offy;
        float px = (float)(w - 1 + kj) + offx;
        float y0f = floorf(py), x0f = floorf(px);
        float ly = py - y0f, lx = px - x0f;
        float hy = 1.f - ly, hx = 1.f - lx;
        int y0 = (int)y0f, x0 = (int)x0f;
        int y1 = y0 + 1,   x1 = x0 + 1;

        bool vy0 = (unsigned)y0 < (unsigned)HH;
        bool vy1 = (unsigned)y1 < (unsigned)HH;
        bool vx0 = (unsigned)x0 < (unsigned)WW;
        bool vx1 = (unsigned)x1 < (unsigned)WW;
        int y0c = min(max(y0, 0), HH - 1);
        int y1c = min(max(y1, 0), HH - 1);
        int x0c = min(max(x0, 0), WW - 1);
        int x1c = min(max(x1, 0), WW - 1);

        float w00 = hy * hx * mval * (float)(vy0 && vx0);
        float w01 = hy * lx * mval * (float)(vy0 && vx1);
        float w10 = ly * hx * mval * (float)(vy1 && vx0);
        float w11 = ly * lx * mval * (float)(vy1 && vx1);

        int i00 = y0c * WW + x0c;
        int i01 = y0c * WW + x1c;
        int i10 = y1c * WW + x0c;
        int i11 = y1c * WW + x1c;

        const float* xb = xb0;
#pragma unroll
        for (int c = 0; c < 16; ++c) {
            acc[c] = fmaf(w00, xb[i00],
                     fmaf(w01, xb[i01],
                     fmaf(w10, xb[i10],
                     fmaf(w11, xb[i11], acc[c]))));
            xb += HWSZ;
        }
    }

    float* ob = out + ((size_t)b * CC + c0) * HWSZ + hw;
#pragma unroll
    for (int c = 0; c < 16; ++c) ob[c * HWSZ] = acc[c];
}

extern "C" void kernel_launch(void* const* d_in, const int* in_sizes, int n_in,
                              void* d_out, int out_size, void* d_ws, size_t ws_size,
                              hipStream_t stream) {
    const float* x      = (const float*)d_in[0];
    const float* offset = (const float*)d_in[1];
    const float* mask   = (const float*)d_in[2];
    const float* weight = (const float*)d_in[3];
    float* out = (float*)d_out;

    const size_t xT_bytes = (size_t)BB * CC * HWSZ * sizeof(__half);
    if (ws_size >= xT_bytes) {
        __half* xT = (__half*)d_ws;
        dim3 tgrid(BB * HH, WW / 64);
        transpose_nchw_to_nhwc_f16<<<tgrid, 256, 0, stream>>>(x, xT);
        dcn_lds<<<BB * (HH / TH) * (WW / TW) * 2, 256, 0, stream>>>(
            xT, offset, mask, weight, out);
    } else {
        dim3 grid(BB * HH, CC / 16);
        dcn_kernel<<<grid, 256, 0, stream>>>(x, offset, mask, weight, out);
    }
}